// Round 9
// baseline (1344.005 us; speedup 1.0000x reference)
//
#include <hip/hip_runtime.h>

// RNN: h_t = tanh(x[b,t]*W_ih + b_ih + b_hh + h_{t-1} @ W_hh^T), out = h_T @ W_out^T + b_out
// B=256 T=2048 H=256 P=24, fp32. One WG/batch (256 WGs = 256 CUs).
//
// Round-9: 256 threads / 4 waves / ~1 wave per SIMD (vs 8 waves before).
// R8's wall was the per-step barrier convoy: 8 waves dumping 32 ds_read_b128
// into one DS pipe (~384 cyc) while SIMDs idle, then a serial finalize tail.
// Now thread (c=tid&15, g=tid>>4) owns a 16x16 W_hh tile: rows 16g..16g+15,
// cols [16c,16c+16). 256 weight floats/thread (~40 overflow into AGPRs --
// CDNA VALU reads AGPRs directly, unified RF). DS reads halve; wave owns its
// SIMD so the FMA stream never competes with a sibling wave.
// Select-free butterfly generalized to 16 slots: slot s holds row
// 16g + (c ^ m[s]), m = {0,1,2,3,7,6,5,4,8,9,10,11,15,14,13,12}; reduction =
// 15 fused v_add_f32_dpp (8x ror8=xor8, 4x half_mirror=xor7, 2x quad 0x4E=xor2,
// 1x quad 0xB1=xor1), zero cndmasks; lane's final value IS row tid -> every
// lane writes its own h (no redundant tanh). One barrier/step.
// h padded (HSTR=20): b128 reads 16B-aligned, <=2-way read aliasing (free).

#define BB 256
#define TT 2048
#define HH 256
#define PP 24
#define HSTR 20   // h chunk stride: 16 data + 4 pad floats

typedef float v2f __attribute__((ext_vector_type(2)));

__device__ __forceinline__ int hidx(int k) { return (k >> 4) * HSTR + (k & 15); }

template<int CTRL>
__device__ __forceinline__ float dppadd(float dst, float src) {
    return dst + __int_as_float(__builtin_amdgcn_update_dpp(
        0, __float_as_int(src), CTRL, 0xf, 0xf, true));
}

__global__ __launch_bounds__(256, 1)
void rnn_persist(const float* __restrict__ x,
                 const float* __restrict__ W_ih,
                 const float* __restrict__ W_hh,
                 const float* __restrict__ b_ih,
                 const float* __restrict__ b_hh,
                 const float* __restrict__ W_out,
                 const float* __restrict__ b_out,
                 float* __restrict__ out)
{
    __shared__ __align__(16) float hbuf[2][16 * HSTR];   // 2 x 1.25 KB

    const int tid = threadIdx.x;
    const int b   = blockIdx.x;
    const int c   = tid & 15;    // K-chunk 0..15 (DPP row lane)
    const int g   = tid >> 4;    // row group 0..15 (rows 16g..16g+15)

    hbuf[0][hidx(tid)] = 0.0f;   // h_0 = 0 (all 256 slots)

    // Slot->row permutation for the 4-level select-free butterfly.
    const int m[16] = {0, 1, 2, 3, 7, 6, 5, 4, 8, 9, 10, 11, 15, 14, 13, 12};

    // Weights: slot s holds row 16g + (c ^ m[s]), cols 16c..16c+15. 256 floats.
    v2f w2[16][8];
    #pragma unroll
    for (int s = 0; s < 16; ++s) {
        const int row_idx = 16 * g + (c ^ m[s]);
        const float* row = W_hh + row_idx * HH + 16 * c;
        #pragma unroll
        for (int j = 0; j < 4; ++j) {
            const float4 q = *(const float4*)(row + 4 * j);
            w2[s][2 * j + 0] = (v2f){q.x, q.y};
            w2[s][2 * j + 1] = (v2f){q.z, q.w};
        }
    }

    // This lane finalizes exactly row o = tid.
    const float wih  = W_ih[tid];
    const float cb   = b_ih[tid] + b_hh[tid];
    const int   widx = hidx(tid);

    __syncthreads();

    const float* hc0 = hbuf[0] + c * HSTR;
    const float* hc1 = hbuf[1] + c * HSTR;
    const float* xb  = x + b * TT;   // uniform address stream -> s_load

    auto step = [&](const float* __restrict__ cur, float* __restrict__ nxt,
                    float xt) __attribute__((always_inline)) {
        const float4* h4p = (const float4*)cur;
        const float4 qa = h4p[0], qb = h4p[1], qc = h4p[2], qd = h4p[3];
        v2f h2[8];
        h2[0] = (v2f){qa.x, qa.y}; h2[1] = (v2f){qa.z, qa.w};
        h2[2] = (v2f){qb.x, qb.y}; h2[3] = (v2f){qb.z, qb.w};
        h2[4] = (v2f){qc.x, qc.y}; h2[5] = (v2f){qc.z, qc.w};
        h2[6] = (v2f){qd.x, qd.y}; h2[7] = (v2f){qd.z, qd.w};

        float aa[16];
        #pragma unroll
        for (int s = 0; s < 16; ++s) {
            v2f acc = w2[s][0] * h2[0];
            #pragma unroll
            for (int j = 1; j < 8; ++j)
                acc = __builtin_elementwise_fma(w2[s][j], h2[j], acc);
            aa[s] = acc.x + acc.y;
        }

        // 4-level select-free merging butterfly: 15 fused DPP adds.
        float bb[8];
        #pragma unroll
        for (int i = 0; i < 8; ++i) bb[i] = dppadd<0x128>(aa[i], aa[i + 8]); // xor8
        float cc[4];
        #pragma unroll
        for (int i = 0; i < 4; ++i) cc[i] = dppadd<0x141>(bb[i], bb[i + 4]); // xor7
        float dd[2];
        #pragma unroll
        for (int i = 0; i < 2; ++i) dd[i] = dppadd<0x4E>(cc[i], cc[i + 2]);  // xor2
        const float e = dppadd<0xB1>(dd[0], dd[1]);                          // xor1

        // tanh(u) = 1 - 2/(e^{2u}+1); exp2 saturates to +-1 at large |u|.
        const float u  = fmaf(xt, wih, cb) + e;
        const float p  = __builtin_amdgcn_exp2f(u * 2.8853900817779268f);
        const float th = fmaf(-2.f, __builtin_amdgcn_rcpf(p + 1.f), 1.f);
        nxt[widx] = th;            // every lane writes its own row
        __syncthreads();
    };

    for (int t = 0; t < TT; t += 4) {
        const float x0 = xb[t + 0];
        const float x1 = xb[t + 1];
        const float x2 = xb[t + 2];
        const float x3 = xb[t + 3];
        step(hc0, hbuf[1], x0);
        step(hc1, hbuf[0], x1);
        step(hc0, hbuf[1], x2);
        step(hc1, hbuf[0], x3);
    }

    // Head: h_T in hbuf[0] (TT % 4 == 0). out[b,p] = b_out[p] + W_out[p,:].h_T
    if (tid < PP) {
        const float* wo = W_out + tid * HH;
        float s0 = 0.f, s1 = 0.f, s2 = 0.f, s3 = 0.f;
        #pragma unroll
        for (int h = 0; h < HH; h += 4) {
            s0 = fmaf(wo[h + 0], hbuf[0][hidx(h + 0)], s0);
            s1 = fmaf(wo[h + 1], hbuf[0][hidx(h + 1)], s1);
            s2 = fmaf(wo[h + 2], hbuf[0][hidx(h + 2)], s2);
            s3 = fmaf(wo[h + 3], hbuf[0][hidx(h + 3)], s3);
        }
        out[b * PP + tid] = b_out[tid] + (s0 + s1) + (s2 + s3);
    }
}

extern "C" void kernel_launch(void* const* d_in, const int* in_sizes, int n_in,
                              void* d_out, int out_size, void* d_ws, size_t ws_size,
                              hipStream_t stream) {
    const float* x     = (const float*)d_in[0];
    const float* W_ih  = (const float*)d_in[1];
    const float* W_hh  = (const float*)d_in[2];
    const float* b_ih  = (const float*)d_in[3];
    const float* b_hh  = (const float*)d_in[4];
    const float* W_out = (const float*)d_in[5];
    const float* b_out = (const float*)d_in[6];
    float* out = (float*)d_out;

    rnn_persist<<<BB, 256, 0, stream>>>(x, W_ih, W_hh, b_ih, b_hh, W_out, b_out, out);
}

// Round 10
// 980.077 us; speedup vs baseline: 1.3713x; 1.3713x over previous
//
#include <hip/hip_runtime.h>

// RNN: h_t = tanh(x[b,t]*W_ih + b_ih + b_hh + h_{t-1} @ W_hh^T), out = h_T @ W_out^T + b_out
// B=256 T=2048 H=256 P=24, fp32. One WG/batch (256 WGs = 256 CUs), 512 thr, 8 waves.
//
// Round-10: de-fatted R8. Lessons locked in: 128 weight floats/lane max (256
// spills to scratch — R9, WRITE_SIZE 6.7MB); 8-wave/512-thr is the working
// structure. Changes vs R8:
//  (1) h read as aligned {v2f lo,hi} quads straight from LDS -> no repack movs
//      (~16 v_mov/wave/step removed).
//  (2) unroll 8; x fetched as two s_load_dwordx4 at iteration top (1 uniform
//      fetch / 8 steps, ~600 cyc of latency hiding vs per-step s_load).
//  (3) after the final xor1 DPP both lane parities hold bit-identical row sums
//      -> ALL lanes write h (2-way same-address LDS write is free), no exec
//      predicate.
// Core: select-free DPP butterfly (slot s holds row (c^m[s])>>1,
// m={0,2,7,5,8,10,15,13}); reduction = 8 fused v_add_f32_dpp, zero cndmasks.
// Lane finalizes row 8g+(c>>1). One barrier/step. HSTR=20 padding.

#define BB 256
#define TT 2048
#define HH 256
#define PP 24
#define HSTR 20   // h chunk stride: 16 data + 4 pad floats (80 B = 5 x 16 B, aligned)

typedef float v2f __attribute__((ext_vector_type(2)));

struct alignas(16) hquad { v2f lo, hi; };   // one ds_read_b128

__device__ __forceinline__ int hidx(int k) { return (k >> 4) * HSTR + (k & 15); }

template<int CTRL>
__device__ __forceinline__ float dppadd(float dst, float src) {
    return dst + __int_as_float(__builtin_amdgcn_update_dpp(
        0, __float_as_int(src), CTRL, 0xf, 0xf, true));
}

__global__ __launch_bounds__(512, 2)
void rnn_persist(const float* __restrict__ x,
                 const float* __restrict__ W_ih,
                 const float* __restrict__ W_hh,
                 const float* __restrict__ b_ih,
                 const float* __restrict__ b_hh,
                 const float* __restrict__ W_out,
                 const float* __restrict__ b_out,
                 float* __restrict__ out)
{
    __shared__ __align__(16) float hbuf[2][16 * HSTR];   // 2 x 1.25 KB

    const int tid = threadIdx.x;
    const int b   = blockIdx.x;
    const int c   = tid & 15;    // K-chunk 0..15 (DPP row lane)
    const int g   = tid >> 4;    // row group (rows 8g..8g+7)

    hbuf[0][hidx(tid & 255)] = 0.0f;   // h_0 = 0 (both halves write, same value)

    // Slot->row permutation for the select-free butterfly.
    const int m[8] = {0, 2, 7, 5, 8, 10, 15, 13};

    // Weights: slot s holds row 8g + ((c^m[s])>>1), cols 16c..16c+15. 128 regs.
    v2f w2[8][8];
    #pragma unroll
    for (int s = 0; s < 8; ++s) {
        const int row_idx = 8 * g + ((c ^ m[s]) >> 1);
        const float* row = W_hh + row_idx * HH + 16 * c;
        #pragma unroll
        for (int j = 0; j < 4; ++j) {
            const float4 q = *(const float4*)(row + 4 * j);
            w2[s][2 * j + 0] = (v2f){q.x, q.y};
            w2[s][2 * j + 1] = (v2f){q.z, q.w};
        }
    }

    // Row this lane finalizes: o = 8g + (c>>1) (both parities agree).
    const int   o_fin = 8 * g + (c >> 1);
    const float wih   = W_ih[o_fin];
    const float cb    = b_ih[o_fin] + b_hh[o_fin];
    const int   widx  = hidx(o_fin);

    __syncthreads();

    const float* hc0 = hbuf[0] + c * HSTR;
    const float* hc1 = hbuf[1] + c * HSTR;
    const float* xb  = x + b * TT;   // uniform address stream -> s_load

    auto step = [&](const float* __restrict__ cur, float* __restrict__ nxt,
                    float xt) __attribute__((always_inline)) {
        const hquad* hq = (const hquad*)cur;
        const hquad q0 = hq[0], q1 = hq[1], q2 = hq[2], q3 = hq[3];

        float aa[8];
        #pragma unroll
        for (int s = 0; s < 8; ++s) {
            v2f acc = w2[s][0] * q0.lo;
            acc = __builtin_elementwise_fma(w2[s][1], q0.hi, acc);
            acc = __builtin_elementwise_fma(w2[s][2], q1.lo, acc);
            acc = __builtin_elementwise_fma(w2[s][3], q1.hi, acc);
            acc = __builtin_elementwise_fma(w2[s][4], q2.lo, acc);
            acc = __builtin_elementwise_fma(w2[s][5], q2.hi, acc);
            acc = __builtin_elementwise_fma(w2[s][6], q3.lo, acc);
            acc = __builtin_elementwise_fma(w2[s][7], q3.hi, acc);
            aa[s] = acc.x + acc.y;
        }

        // Select-free butterfly: 8 fused DPP adds, no cndmasks.
        float b0 = dppadd<0x128>(aa[0], aa[4]);   // xor8 (row_ror:8)
        float b1 = dppadd<0x128>(aa[1], aa[5]);
        float b2 = dppadd<0x128>(aa[2], aa[6]);
        float b3 = dppadd<0x128>(aa[3], aa[7]);
        float c0 = dppadd<0x141>(b0, b2);         // xor7 (row_half_mirror)
        float c1 = dppadd<0x141>(b1, b3);
        float d  = dppadd<0x4E>(c0, c1);          // xor2 (quad_perm 2,3,0,1)
        float e  = dppadd<0xB1>(d, d);            // xor1 (quad_perm 1,0,3,2)

        // tanh(u) = 1 - 2/(e^{2u}+1); exp2 saturates cleanly at large |u|.
        const float u  = fmaf(xt, wih, cb) + e;
        const float p  = __builtin_amdgcn_exp2f(u * 2.8853900817779268f);
        const float th = fmaf(-2.f, __builtin_amdgcn_rcpf(p + 1.f), 1.f);
        nxt[widx] = th;   // both parities write identical value (2-way, free)
        __syncthreads();
    };

    for (int t = 0; t < TT; t += 8) {
        const float4 xa = *(const float4*)(xb + t);
        const float4 xc = *(const float4*)(xb + t + 4);
        step(hc0, hbuf[1], xa.x);
        step(hc1, hbuf[0], xa.y);
        step(hc0, hbuf[1], xa.z);
        step(hc1, hbuf[0], xa.w);
        step(hc0, hbuf[1], xc.x);
        step(hc1, hbuf[0], xc.y);
        step(hc0, hbuf[1], xc.z);
        step(hc1, hbuf[0], xc.w);
    }

    // Head: h_T in hbuf[0] (TT % 8 == 0). out[b,p] = b_out[p] + W_out[p,:].h_T
    if (tid < PP) {
        const float* wo = W_out + tid * HH;
        float s0 = 0.f, s1 = 0.f, s2 = 0.f, s3 = 0.f;
        #pragma unroll
        for (int h = 0; h < HH; h += 4) {
            s0 = fmaf(wo[h + 0], hbuf[0][hidx(h + 0)], s0);
            s1 = fmaf(wo[h + 1], hbuf[0][hidx(h + 1)], s1);
            s2 = fmaf(wo[h + 2], hbuf[0][hidx(h + 2)], s2);
            s3 = fmaf(wo[h + 3], hbuf[0][hidx(h + 3)], s3);
        }
        out[b * PP + tid] = b_out[tid] + (s0 + s1) + (s2 + s3);
    }
}

extern "C" void kernel_launch(void* const* d_in, const int* in_sizes, int n_in,
                              void* d_out, int out_size, void* d_ws, size_t ws_size,
                              hipStream_t stream) {
    const float* x     = (const float*)d_in[0];
    const float* W_ih  = (const float*)d_in[1];
    const float* W_hh  = (const float*)d_in[2];
    const float* b_ih  = (const float*)d_in[3];
    const float* b_hh  = (const float*)d_in[4];
    const float* W_out = (const float*)d_in[5];
    const float* b_out = (const float*)d_in[6];
    float* out = (float*)d_out;

    rnn_persist<<<BB, 512, 0, stream>>>(x, W_ih, W_hh, b_ih, b_hh, W_out, b_out, out);
}

// Round 11
// 971.018 us; speedup vs baseline: 1.3841x; 1.0093x over previous
//
#include <hip/hip_runtime.h>

// RNN: h_t = tanh(x[b,t]*W_ih + b_ih + b_hh + h_{t-1} @ W_hh^T), out = h_T @ W_out^T + b_out
// B=256 T=2048 H=256 P=24, fp32. One WG/batch (256 WGs = 256 CUs), 512 thr, 8 waves.
//
// Round-11: R10 + x block-prefetch. R10's step = 1148 cyc: 512 FMA floor +
// ~400 DS convoy + tail, nearly serialized (one-barrier all-to-all structure).
// The s_load x-fetch at each 8-step block top sat on the critical path
// (~200 cyc L2 latency + lgkmcnt entanglement every 8 steps). Now block t's
// x was fetched at block t-8's top: the wait is satisfied by consumption time.
// Locked-in structure: 128 weight floats/lane (256 spills - R9); 512thr/8
// waves; select-free DPP butterfly (slot s holds row (c^m[s])>>1,
// m={0,2,7,5,8,10,15,13}; 8 fused v_add_f32_dpp, zero cndmasks); lane
// finalizes row 8g+(c>>1), all lanes write (2-way same-addr = free);
// one barrier/step; HSTR=20 padding (<=2-way bank aliasing, free).

#define BB 256
#define TT 2048
#define HH 256
#define PP 24
#define HSTR 20   // h chunk stride: 16 data + 4 pad floats

typedef float v2f __attribute__((ext_vector_type(2)));

struct alignas(16) hquad { v2f lo, hi; };   // one ds_read_b128

__device__ __forceinline__ int hidx(int k) { return (k >> 4) * HSTR + (k & 15); }

template<int CTRL>
__device__ __forceinline__ float dppadd(float dst, float src) {
    return dst + __int_as_float(__builtin_amdgcn_update_dpp(
        0, __float_as_int(src), CTRL, 0xf, 0xf, true));
}

__global__ __launch_bounds__(512, 2)
void rnn_persist(const float* __restrict__ x,
                 const float* __restrict__ W_ih,
                 const float* __restrict__ W_hh,
                 const float* __restrict__ b_ih,
                 const float* __restrict__ b_hh,
                 const float* __restrict__ W_out,
                 const float* __restrict__ b_out,
                 float* __restrict__ out)
{
    __shared__ __align__(16) float hbuf[2][16 * HSTR];   // 2 x 1.25 KB

    const int tid = threadIdx.x;
    const int b   = blockIdx.x;
    const int c   = tid & 15;    // K-chunk 0..15 (DPP row lane)
    const int g   = tid >> 4;    // row group (rows 8g..8g+7)

    hbuf[0][hidx(tid & 255)] = 0.0f;   // h_0 = 0 (both halves write, same value)

    // Slot->row permutation for the select-free butterfly.
    const int m[8] = {0, 2, 7, 5, 8, 10, 15, 13};

    // Weights: slot s holds row 8g + ((c^m[s])>>1), cols 16c..16c+15. 128 regs.
    v2f w2[8][8];
    #pragma unroll
    for (int s = 0; s < 8; ++s) {
        const int row_idx = 8 * g + ((c ^ m[s]) >> 1);
        const float* row = W_hh + row_idx * HH + 16 * c;
        #pragma unroll
        for (int j = 0; j < 4; ++j) {
            const float4 q = *(const float4*)(row + 4 * j);
            w2[s][2 * j + 0] = (v2f){q.x, q.y};
            w2[s][2 * j + 1] = (v2f){q.z, q.w};
        }
    }

    // Row this lane finalizes: o = 8g + (c>>1) (both parities agree).
    const int   o_fin = 8 * g + (c >> 1);
    const float wih   = W_ih[o_fin];
    const float cb    = b_ih[o_fin] + b_hh[o_fin];
    const int   widx  = hidx(o_fin);

    __syncthreads();

    const float* hc0 = hbuf[0] + c * HSTR;
    const float* hc1 = hbuf[1] + c * HSTR;
    const float* xb  = x + b * TT;   // uniform address stream -> s_load

    auto step = [&](const float* __restrict__ cur, float* __restrict__ nxt,
                    float xt) __attribute__((always_inline)) {
        const hquad* hq = (const hquad*)cur;
        const hquad q0 = hq[0], q1 = hq[1], q2 = hq[2], q3 = hq[3];

        float aa[8];
        #pragma unroll
        for (int s = 0; s < 8; ++s) {
            v2f acc = w2[s][0] * q0.lo;
            acc = __builtin_elementwise_fma(w2[s][1], q0.hi, acc);
            acc = __builtin_elementwise_fma(w2[s][2], q1.lo, acc);
            acc = __builtin_elementwise_fma(w2[s][3], q1.hi, acc);
            acc = __builtin_elementwise_fma(w2[s][4], q2.lo, acc);
            acc = __builtin_elementwise_fma(w2[s][5], q2.hi, acc);
            acc = __builtin_elementwise_fma(w2[s][6], q3.lo, acc);
            acc = __builtin_elementwise_fma(w2[s][7], q3.hi, acc);
            aa[s] = acc.x + acc.y;
        }

        // Select-free butterfly: 8 fused DPP adds, no cndmasks.
        float b0 = dppadd<0x128>(aa[0], aa[4]);   // xor8 (row_ror:8)
        float b1 = dppadd<0x128>(aa[1], aa[5]);
        float b2 = dppadd<0x128>(aa[2], aa[6]);
        float b3 = dppadd<0x128>(aa[3], aa[7]);
        float c0 = dppadd<0x141>(b0, b2);         // xor7 (row_half_mirror)
        float c1 = dppadd<0x141>(b1, b3);
        float d  = dppadd<0x4E>(c0, c1);          // xor2 (quad_perm 2,3,0,1)
        float e  = dppadd<0xB1>(d, d);            // xor1 (quad_perm 1,0,3,2)

        // tanh(u) = 1 - 2/(e^{2u}+1); exp2 saturates cleanly at large |u|.
        const float u  = fmaf(xt, wih, cb) + e;
        const float p  = __builtin_amdgcn_exp2f(u * 2.8853900817779268f);
        const float th = fmaf(-2.f, __builtin_amdgcn_rcpf(p + 1.f), 1.f);
        nxt[widx] = th;   // both parities write identical value (2-way, free)
        __syncthreads();
    };

    // x block-prefetch: block's two float4s fetched one 8-step block ahead.
    float4 xa = *(const float4*)(xb + 0);
    float4 xc = *(const float4*)(xb + 4);
    for (int t = 0; t < TT; t += 8) {
        const int tn = (t + 8 < TT) ? (t + 8) : t;   // clamped (last block refetch)
        const float4 xa_n = *(const float4*)(xb + tn);
        const float4 xc_n = *(const float4*)(xb + tn + 4);
        step(hc0, hbuf[1], xa.x);
        step(hc1, hbuf[0], xa.y);
        step(hc0, hbuf[1], xa.z);
        step(hc1, hbuf[0], xa.w);
        step(hc0, hbuf[1], xc.x);
        step(hc1, hbuf[0], xc.y);
        step(hc0, hbuf[1], xc.z);
        step(hc1, hbuf[0], xc.w);
        xa = xa_n;
        xc = xc_n;
    }

    // Head: h_T in hbuf[0] (TT % 8 == 0). out[b,p] = b_out[p] + W_out[p,:].h_T
    if (tid < PP) {
        const float* wo = W_out + tid * HH;
        float s0 = 0.f, s1 = 0.f, s2 = 0.f, s3 = 0.f;
        #pragma unroll
        for (int h = 0; h < HH; h += 4) {
            s0 = fmaf(wo[h + 0], hbuf[0][hidx(h + 0)], s0);
            s1 = fmaf(wo[h + 1], hbuf[0][hidx(h + 1)], s1);
            s2 = fmaf(wo[h + 2], hbuf[0][hidx(h + 2)], s2);
            s3 = fmaf(wo[h + 3], hbuf[0][hidx(h + 3)], s3);
        }
        out[b * PP + tid] = b_out[tid] + (s0 + s1) + (s2 + s3);
    }
}

extern "C" void kernel_launch(void* const* d_in, const int* in_sizes, int n_in,
                              void* d_out, int out_size, void* d_ws, size_t ws_size,
                              hipStream_t stream) {
    const float* x     = (const float*)d_in[0];
    const float* W_ih  = (const float*)d_in[1];
    const float* W_hh  = (const float*)d_in[2];
    const float* b_ih  = (const float*)d_in[3];
    const float* b_hh  = (const float*)d_in[4];
    const float* W_out = (const float*)d_in[5];
    const float* b_out = (const float*)d_in[6];
    float* out = (float*)d_out;

    rnn_persist<<<BB, 512, 0, stream>>>(x, W_ih, W_hh, b_ih, b_hh, W_out, b_out, out);
}

// Round 12
// 970.236 us; speedup vs baseline: 1.3852x; 1.0008x over previous
//
#include <hip/hip_runtime.h>

// RNN: h_t = tanh(x[b,t]*W_ih + b_ih + b_hh + h_{t-1} @ W_hh^T), out = h_T @ W_out^T + b_out
// B=256 T=2048 H=256 P=24, fp32. One WG/batch (256 WGs = 256 CUs), 512 thr, 8 waves.
//
// Round-12: j-OUTER FMA loop. R11's convoy: post-barrier DS drain (~400 cyc,
// 32 ds_read_b128/CU) with idle VALU, then FMA burst with idle DS. s-outer
// accumulation consumed q0..q3 serially per slot -> math couldn't start until
// deep lgkmcnt. j-outer updates all 8 accumulators per h-quad: 16 pk_fmas
// issue at lgkmcnt(3) (only q0 landed), overlapping most of the drain.
// Per-accumulator FP order unchanged (j ascending) -> absmax bit-identical.
// Locked-in: 128 weight floats/lane (256 spills — R9); select-free DPP
// butterfly (slot s = row (c^m[s])>>1, m={0,2,7,5,8,10,15,13}; 8 fused
// v_add_f32_dpp, zero cndmasks); lane finalizes row 8g+(c>>1); all lanes
// write h (2-way same-addr free); one barrier/step; HSTR=20 padding;
// x block-prefetched one 8-step block ahead (s_load_dwordx4).

#define BB 256
#define TT 2048
#define HH 256
#define PP 24
#define HSTR 20   // h chunk stride: 16 data + 4 pad floats

typedef float v2f __attribute__((ext_vector_type(2)));

struct alignas(16) hquad { v2f lo, hi; };   // one ds_read_b128

__device__ __forceinline__ int hidx(int k) { return (k >> 4) * HSTR + (k & 15); }

template<int CTRL>
__device__ __forceinline__ float dppadd(float dst, float src) {
    return dst + __int_as_float(__builtin_amdgcn_update_dpp(
        0, __float_as_int(src), CTRL, 0xf, 0xf, true));
}

__global__ __launch_bounds__(512, 2)
void rnn_persist(const float* __restrict__ x,
                 const float* __restrict__ W_ih,
                 const float* __restrict__ W_hh,
                 const float* __restrict__ b_ih,
                 const float* __restrict__ b_hh,
                 const float* __restrict__ W_out,
                 const float* __restrict__ b_out,
                 float* __restrict__ out)
{
    __shared__ __align__(16) float hbuf[2][16 * HSTR];   // 2 x 1.25 KB

    const int tid = threadIdx.x;
    const int b   = blockIdx.x;
    const int c   = tid & 15;    // K-chunk 0..15 (DPP row lane)
    const int g   = tid >> 4;    // row group (rows 8g..8g+7)

    hbuf[0][hidx(tid & 255)] = 0.0f;   // h_0 = 0 (both halves write, same value)

    // Slot->row permutation for the select-free butterfly.
    const int m[8] = {0, 2, 7, 5, 8, 10, 15, 13};

    // Weights: slot s holds row 8g + ((c^m[s])>>1), cols 16c..16c+15. 128 regs.
    v2f w2[8][8];
    #pragma unroll
    for (int s = 0; s < 8; ++s) {
        const int row_idx = 8 * g + ((c ^ m[s]) >> 1);
        const float* row = W_hh + row_idx * HH + 16 * c;
        #pragma unroll
        for (int j = 0; j < 4; ++j) {
            const float4 q = *(const float4*)(row + 4 * j);
            w2[s][2 * j + 0] = (v2f){q.x, q.y};
            w2[s][2 * j + 1] = (v2f){q.z, q.w};
        }
    }

    // Row this lane finalizes: o = 8g + (c>>1) (both parities agree).
    const int   o_fin = 8 * g + (c >> 1);
    const float wih   = W_ih[o_fin];
    const float cb    = b_ih[o_fin] + b_hh[o_fin];
    const int   widx  = hidx(o_fin);

    __syncthreads();

    const float* hc0 = hbuf[0] + c * HSTR;
    const float* hc1 = hbuf[1] + c * HSTR;
    const float* xb  = x + b * TT;   // uniform address stream -> s_load

    auto step = [&](const float* __restrict__ cur, float* __restrict__ nxt,
                    float xt) __attribute__((always_inline)) {
        const hquad* hq = (const hquad*)cur;
        // Issue all 4 reads back-to-back; consume in arrival order (j-outer)
        // so FMAs start at lgkmcnt(3).
        const hquad q0 = hq[0], q1 = hq[1], q2 = hq[2], q3 = hq[3];

        v2f acc[8];
        #pragma unroll
        for (int s = 0; s < 8; ++s) acc[s] = w2[s][0] * q0.lo;       // j=0
        #pragma unroll
        for (int s = 0; s < 8; ++s)
            acc[s] = __builtin_elementwise_fma(w2[s][1], q0.hi, acc[s]);
        #pragma unroll
        for (int s = 0; s < 8; ++s)
            acc[s] = __builtin_elementwise_fma(w2[s][2], q1.lo, acc[s]);
        #pragma unroll
        for (int s = 0; s < 8; ++s)
            acc[s] = __builtin_elementwise_fma(w2[s][3], q1.hi, acc[s]);
        #pragma unroll
        for (int s = 0; s < 8; ++s)
            acc[s] = __builtin_elementwise_fma(w2[s][4], q2.lo, acc[s]);
        #pragma unroll
        for (int s = 0; s < 8; ++s)
            acc[s] = __builtin_elementwise_fma(w2[s][5], q2.hi, acc[s]);
        #pragma unroll
        for (int s = 0; s < 8; ++s)
            acc[s] = __builtin_elementwise_fma(w2[s][6], q3.lo, acc[s]);
        #pragma unroll
        for (int s = 0; s < 8; ++s)
            acc[s] = __builtin_elementwise_fma(w2[s][7], q3.hi, acc[s]);

        float aa[8];
        #pragma unroll
        for (int s = 0; s < 8; ++s) aa[s] = acc[s].x + acc[s].y;

        // Select-free butterfly: 8 fused DPP adds, no cndmasks.
        float b0 = dppadd<0x128>(aa[0], aa[4]);   // xor8 (row_ror:8)
        float b1 = dppadd<0x128>(aa[1], aa[5]);
        float b2 = dppadd<0x128>(aa[2], aa[6]);
        float b3 = dppadd<0x128>(aa[3], aa[7]);
        float c0 = dppadd<0x141>(b0, b2);         // xor7 (row_half_mirror)
        float c1 = dppadd<0x141>(b1, b3);
        float d  = dppadd<0x4E>(c0, c1);          // xor2 (quad_perm 2,3,0,1)
        float e  = dppadd<0xB1>(d, d);            // xor1 (quad_perm 1,0,3,2)

        // tanh(u) = 1 - 2/(e^{2u}+1); exp2 saturates cleanly at large |u|.
        const float u  = fmaf(xt, wih, cb) + e;
        const float p  = __builtin_amdgcn_exp2f(u * 2.8853900817779268f);
        const float th = fmaf(-2.f, __builtin_amdgcn_rcpf(p + 1.f), 1.f);
        nxt[widx] = th;   // both parities write identical value (2-way, free)
        __syncthreads();
    };

    // x block-prefetch: block's two float4s fetched one 8-step block ahead.
    float4 xa = *(const float4*)(xb + 0);
    float4 xc = *(const float4*)(xb + 4);
    for (int t = 0; t < TT; t += 8) {
        const int tn = (t + 8 < TT) ? (t + 8) : t;   // clamped (last block refetch)
        const float4 xa_n = *(const float4*)(xb + tn);
        const float4 xc_n = *(const float4*)(xb + tn + 4);
        step(hc0, hbuf[1], xa.x);
        step(hc1, hbuf[0], xa.y);
        step(hc0, hbuf[1], xa.z);
        step(hc1, hbuf[0], xa.w);
        step(hc0, hbuf[1], xc.x);
        step(hc1, hbuf[0], xc.y);
        step(hc0, hbuf[1], xc.z);
        step(hc1, hbuf[0], xc.w);
        xa = xa_n;
        xc = xc_n;
    }

    // Head: h_T in hbuf[0] (TT % 8 == 0). out[b,p] = b_out[p] + W_out[p,:].h_T
    if (tid < PP) {
        const float* wo = W_out + tid * HH;
        float s0 = 0.f, s1 = 0.f, s2 = 0.f, s3 = 0.f;
        #pragma unroll
        for (int h = 0; h < HH; h += 4) {
            s0 = fmaf(wo[h + 0], hbuf[0][hidx(h + 0)], s0);
            s1 = fmaf(wo[h + 1], hbuf[0][hidx(h + 1)], s1);
            s2 = fmaf(wo[h + 2], hbuf[0][hidx(h + 2)], s2);
            s3 = fmaf(wo[h + 3], hbuf[0][hidx(h + 3)], s3);
        }
        out[b * PP + tid] = b_out[tid] + (s0 + s1) + (s2 + s3);
    }
}

extern "C" void kernel_launch(void* const* d_in, const int* in_sizes, int n_in,
                              void* d_out, int out_size, void* d_ws, size_t ws_size,
                              hipStream_t stream) {
    const float* x     = (const float*)d_in[0];
    const float* W_ih  = (const float*)d_in[1];
    const float* W_hh  = (const float*)d_in[2];
    const float* b_ih  = (const float*)d_in[3];
    const float* b_hh  = (const float*)d_in[4];
    const float* W_out = (const float*)d_in[5];
    const float* b_out = (const float*)d_in[6];
    float* out = (float*)d_out;

    rnn_persist<<<BB, 512, 0, stream>>>(x, W_ih, W_hh, b_ih, b_hh, W_out, b_out, out);
}